// Round 8
// baseline (125.841 us; speedup 1.0000x reference)
//
#include <hip/hip_runtime.h>

#define B_ 16
#define N_ 1024
#define DIN 256
#define K_ 24
#define D_ 128
#define KD_ 3072
#define NSPLIT 16
#define NCHUNK 64
#define EPS_ 1e-7f
#define NBLK 256
#define NUNIT (B_ * K_)  /* 384 */

// Coherent (cross-XCD) data accessors: relaxed agent-scope atomics -> single
// sc1 load/store instructions. Consumers always cload (bypass stale L2).
__device__ __forceinline__ float cload(const float* p) {
    return __hip_atomic_load(p, __ATOMIC_RELAXED, __HIP_MEMORY_SCOPE_AGENT);
}
__device__ __forceinline__ void cstore(float* p, float v) {
    __hip_atomic_store(p, v, __ATOMIC_RELAXED, __HIP_MEMORY_SCOPE_AGENT);
}

// ---- per-batch producer/consumer flags
// F1[j][b]: tpart(iter j) ready, target 16.  F2[j][b]: w2(iter j) ready, target 24.
__device__ __forceinline__ unsigned* F1p(unsigned* f, int j, int b) {
    return f + (j * 16 + b) * 16;
}
__device__ __forceinline__ unsigned* F2p(unsigned* f, int j, int b) {
    return f + 768 + (j * 16 + b) * 16;
}
// RELEASE: orders this block's prior sc1 data stores to MALL before the flag
// increment becomes visible (r7's relaxed version raced: absmax drifted).
__device__ __forceinline__ void flag_add(unsigned* f) {
    asm volatile("" ::: "memory");
    __hip_atomic_fetch_add(f, 1u, __ATOMIC_RELEASE, __HIP_MEMORY_SCOPE_AGENT);
}
__device__ __forceinline__ void flag_wait(unsigned* f, unsigned target) {
    while (__hip_atomic_load(f, __ATOMIC_RELAXED, __HIP_MEMORY_SCOPE_AGENT) < target)
        __builtin_amdgcn_s_sleep(1);
    asm volatile("" ::: "memory");
}

// ---- sv phase (1024 thr): t-reduce, s = t@W_k, v = squash(s), w2 = v@W_k^T
__device__ __forceinline__ void sv_phase(int iter, int beta, int t,
                                         const float* __restrict__ W,
                                         const float* __restrict__ tupart,
                                         const float* __restrict__ tpart,
                                         float* __restrict__ w2,
                                         float* __restrict__ out,
                                         float* shbuf, unsigned* flg) {
    float* t_lds = shbuf;           // [256]
    float* sred  = shbuf + 256;     // [8][128]
    float* red2  = shbuf + 1280;    // [2]
    float* v_lds = shbuf + 1284;    // [128], 16B aligned (1284*4 % 16 == 0)
    for (int unit = beta; unit < NUNIT; unit += NBLK) {
        const int b = unit / K_, k = unit % K_;
        if (t == 0) flag_wait(F1p(flg, iter, b), 16);
        __syncthreads();  // release block; also protects shbuf reuse
        // t-reduce: 256 threads, 16 coherent loads each (pipelined)
        if (t < DIN) {
            float a = 0.f;
            if (iter == 0) {
                #pragma unroll
                for (int s2 = 0; s2 < NSPLIT; ++s2)
                    a += cload(tupart + ((size_t)(b * NSPLIT + s2)) * DIN + t);
                a *= (1.0f / 24.0f);
            } else {
                #pragma unroll
                for (int s2 = 0; s2 < NSPLIT; ++s2)
                    a += cload(tpart + ((size_t)((b * NSPLIT + s2) * K_ + k)) * DIN + t);
            }
            t_lds[t] = a;
        }
        __syncthreads();
        // s_d = sum_i t[i]*W[i,k*128+d]; 1024 thr: d = t&127, i-eighth q = t>>7
        {
            const int d = t & (D_ - 1), q = t >> 7;
            const float* Wp = W + (size_t)(q * 32) * KD_ + (size_t)k * D_ + d;
            const float* tp = t_lds + q * 32;
            float sd = 0.f;
            #pragma unroll 8
            for (int i = 0; i < 32; ++i) sd += tp[i] * Wp[(size_t)i * KD_];
            sred[q * D_ + d] = sd;
        }
        __syncthreads();
        float sd = 0.f;
        if (t < D_) {
            #pragma unroll
            for (int q = 0; q < 8; ++q) sd += sred[q * D_ + t];
            float sq = sd * sd;
            #pragma unroll
            for (int m = 1; m < 64; m <<= 1) sq += __shfl_xor(sq, m);
            if ((t & 63) == 0) red2[t >> 6] = sq;
        }
        __syncthreads();
        const float inv = rsqrtf(red2[0] + red2[1] + EPS_);
        if (t < D_) {
            const float vd = sd * inv;
            v_lds[t] = vd;
            if (iter == 2) out[((size_t)(b * K_ + k)) * D_ + t] = vd;
        }
        __syncthreads();
        if (iter != 2) {
            // w2[i] = sum_d v[d]*W[i,k*128+d]; 4-lane groups: i = t>>2, dq = t&3
            const int i = t >> 2, dq = t & 3;
            const float4* Wq = (const float4*)(W + (size_t)i * KD_ + (size_t)k * D_ + dq * 32);
            const float4* vq = (const float4*)(v_lds + dq * 32);
            float a = 0.f;
            #pragma unroll
            for (int m = 0; m < 8; ++m) {
                float4 wv = Wq[m], vv = vq[m];
                a += wv.x * vv.x + wv.y * vv.y + wv.z * vv.z + wv.w * vv.w;
            }
            a += __shfl_xor(a, 1);
            a += __shfl_xor(a, 2);
            if (dq == 0) cstore(w2 + ((size_t)(b * K_ + k)) * DIN + i, a);
            __syncthreads();  // drain w2 stores before flagging
            if (t == 0) flag_add(F2p(flg, iter, b));
        }
    }
}

// ---- fused phase (1024 thr): logits + in-register softmax + t-partials
__device__ __forceinline__ void fused_phase(int iter, int b, int s, int t,
                                            const float* __restrict__ w2,
                                            float* __restrict__ tpart,
                                            const float* u_lds, float* shbuf,
                                            float* w2_lds, unsigned* flg) {
    if (t == 0) flag_wait(F2p(flg, iter - 1, b), 24);
    __syncthreads();
    // stage w2[b] (24 KB) into LDS
    {
        const float* w2g = w2 + (size_t)b * K_ * DIN;
        #pragma unroll
        for (int r = 0; r < 6; ++r)
            w2_lds[t + r * 1024] = cload(w2g + t + r * 1024);
    }
    __syncthreads();

    // phase 1: logits + softmax fully in-register.
    // thread (n = t>>4, p = t&15) covers i in {p*4 + g*64 + m}: interleaved
    // partition -> conflict-free LDS; 16-lane shfl butterfly completes sum_i.
    float* c_lds = shbuf;  // [64][28]
    {
        const int n = t >> 4, p = t & 15;
        float acc[K_];
        #pragma unroll
        for (int k = 0; k < K_; ++k) acc[k] = 0.f;
        #pragma unroll
        for (int g = 0; g < 4; ++g) {
            const int i0 = p * 4 + g * 64;
            const float ua0 = u_lds[n * 257 + i0 + 0];
            const float ua1 = u_lds[n * 257 + i0 + 1];
            const float ua2 = u_lds[n * 257 + i0 + 2];
            const float ua3 = u_lds[n * 257 + i0 + 3];
            #pragma unroll
            for (int k = 0; k < K_; ++k) {
                const float4 wq = *(const float4*)(w2_lds + k * DIN + i0);
                acc[k] += ua0 * wq.x + ua1 * wq.y + ua2 * wq.z + ua3 * wq.w;
            }
        }
        #pragma unroll
        for (int m = 1; m < 16; m <<= 1)
            #pragma unroll
            for (int k = 0; k < K_; ++k) acc[k] += __shfl_xor(acc[k], m);
        // per-thread softmax over 24 logits (redundant across p, deterministic)
        float mx = acc[0];
        #pragma unroll
        for (int k = 1; k < K_; ++k) mx = fmaxf(mx, acc[k]);
        float sm = 0.f;
        #pragma unroll
        for (int k = 0; k < K_; ++k) { acc[k] = __expf(acc[k] - mx); sm += acc[k]; }
        const float inv = 1.0f / sm;
        if (p < 8) {
            c_lds[n * 28 + p * 3 + 0] = acc[p * 3 + 0] * inv;
            c_lds[n * 28 + p * 3 + 1] = acc[p * 3 + 1] * inv;
            c_lds[n * 28 + p * 3 + 2] = acc[p * 3 + 2] * inv;
        }
    }
    __syncthreads();

    // phase 3: tpart[k][i] = sum_n c[n][k]*u[n][i]; k-split kg = t>>8 (6 k each)
    {
        const int i = t & 255, kg = t >> 8;
        float a0 = 0.f, a1 = 0.f, a2 = 0.f, a3 = 0.f, a4 = 0.f, a5 = 0.f;
        #pragma unroll 4
        for (int n = 0; n < NCHUNK; ++n) {
            const float uv = u_lds[n * 257 + i];
            const float* cr = c_lds + n * 28 + kg * 6;
            a0 += uv * cr[0]; a1 += uv * cr[1]; a2 += uv * cr[2];
            a3 += uv * cr[3]; a4 += uv * cr[4]; a5 += uv * cr[5];
        }
        float* tp = tpart + ((size_t)((b * NSPLIT + s) * K_ + kg * 6)) * DIN + i;
        cstore(tp + 0 * DIN, a0); cstore(tp + 1 * DIN, a1);
        cstore(tp + 2 * DIN, a2); cstore(tp + 3 * DIN, a3);
        cstore(tp + 4 * DIN, a4); cstore(tp + 5 * DIN, a5);
    }
    __syncthreads();  // drain tpart stores before flagging
    if (t == 0) flag_add(F1p(flg, iter, b));
}

__global__ __launch_bounds__(1024, 4) void k_caps(const float* __restrict__ u,
                                                  const float* __restrict__ W,
                                                  float* __restrict__ out,
                                                  float* __restrict__ tupart,
                                                  float* __restrict__ tpart,
                                                  float* __restrict__ w2,
                                                  unsigned* __restrict__ flg) {
    const int beta = blockIdx.x;
    const int b = beta >> 4, s = beta & 15;
    const int t = threadIdx.x;

    __shared__ float u_lds[NCHUNK * 257];              // 65,792 B (persistent)
    __shared__ __align__(16) float w2_lds[K_ * DIN];   // 24,576 B
    __shared__ __align__(16) float shbuf[1792];        //  7,168 B (c_lds / sv scratch)

    // ---- P0: stage u chunk (persistent); colsum -> tupart (iter-0 t, c uniform)
    {
        const float4* ug = (const float4*)(u + ((size_t)(b * N_ + s * NCHUNK)) * DIN);
        #pragma unroll
        for (int r = 0; r < 4; ++r) {
            const int idx = t + r * 1024;
            const int n = idx >> 6, q = idx & 63;
            float4 v = ug[(size_t)n * 64 + q];
            float* dst = u_lds + n * 257 + q * 4;
            dst[0] = v.x; dst[1] = v.y; dst[2] = v.z; dst[3] = v.w;
        }
        __syncthreads();
        if (t < DIN) {
            float a = 0.f;
            #pragma unroll
            for (int n = 0; n < NCHUNK; ++n) a += u_lds[n * 257 + t];
            cstore(tupart + ((size_t)(b * NSPLIT + s)) * DIN + t, a);
        }
        __syncthreads();  // drain tupart stores
        if (t == 0) flag_add(F1p(flg, 0, b));
    }

    // ---- iter 0
    sv_phase(0, beta, t, W, tupart, tpart, w2, out, shbuf, flg);
    // ---- iter 1
    fused_phase(1, b, s, t, w2, tpart, u_lds, shbuf, w2_lds, flg);
    sv_phase(1, beta, t, W, tupart, tpart, w2, out, shbuf, flg);
    // ---- iter 2
    fused_phase(2, b, s, t, w2, tpart, u_lds, shbuf, w2_lds, flg);
    sv_phase(2, beta, t, W, tupart, tpart, w2, out, shbuf, flg);
}

extern "C" void kernel_launch(void* const* d_in, const int* in_sizes, int n_in,
                              void* d_out, int out_size, void* d_ws, size_t ws_size,
                              hipStream_t stream) {
    const float* u = (const float*)d_in[0];   // [16,1024,256]
    const float* W = (const float*)d_in[1];   // [256,3072]
    float* out = (float*)d_out;               // [16,24,128]

    char* ws = (char*)d_ws;
    float* tpart    = (float*)ws;                              // 6,291,456 B
    float* w2       = (float*)(ws + 6291456);                  //   393,216 B
    float* tupart   = (float*)(ws + 6291456 + 393216);         //   262,144 B
    unsigned* flg   = (unsigned*)(ws + 6946816);               //     6,144 B

    // zero the flags (captured into the graph, so every replay resets them)
    hipMemsetAsync(flg, 0, 6144, stream);

    void* args[] = {(void*)&u, (void*)&W, (void*)&out,
                    (void*)&tupart, (void*)&tpart, (void*)&w2, (void*)&flg};
    hipLaunchCooperativeKernel(reinterpret_cast<void*>(k_caps),
                               dim3(NBLK), dim3(1024), args, 0, stream);
}